// Round 11
// baseline (67.334 us; speedup 1.0000x reference)
//
#include <hip/hip_runtime.h>
#include <math.h>

#define NJ 4         // odd powers x^1..x^7
#define DEG 7
#define X0f 1.1f     // poly valid on [-1.1,1.1]; typical |s*g| ~ 0.4
#define NB 8         // batch rows per block
#define NT 768       // threads per block (12 waves)

struct Poly { float c[NJ]; };

#define FMA4(A,S,W) do { (A).x = fmaf((S),(W).x,(A).x); (A).y = fmaf((S),(W).y,(A).y); \
                         (A).z = fmaf((S),(W).z,(A).z); (A).w = fmaf((S),(W).w,(A).w); } while(0)

// ---------------- K0: repack weights ----------------
__global__ __launch_bounds__(256) void k_repack(
    const float* __restrict__ Wc, const float* __restrict__ W1,
    const float* __restrict__ eW0, const float* __restrict__ eW1, const float* __restrict__ eW2,
    float* __restrict__ WcT, float* __restrict__ W1T,
    float* __restrict__ Wt0, float* __restrict__ Wt1, float* __restrict__ Wt2) {
    int tid = blockIdx.x * 256 + threadIdx.x;
    int stride = gridDim.x * 256;
    for (int idx = tid; idx < 3 * 464 * 32; idx += stride) {
        int i = idx / (464 * 32); int rem = idx - i * 464 * 32;
        int m = rem >> 5, h = rem & 31;
        float v = 0.f;
        if (m < 456) {
            int seg = m / 152, e = m - seg * 152;
            if (e < 150) v = Wc[((size_t)i * 32 + h) * 450 + seg * 150 + e];
        }
        WcT[idx] = v;
    }
    for (int idx = tid; idx < 456 * 128; idx += stride) {
        int m = idx >> 7, k = idx & 127;
        int seg = m / 152, e = m - seg * 152;
        W1T[idx] = (e < 150) ? W1[k * 450 + seg * 150 + e] : 0.f;
    }
    for (int idx = tid; idx < 304 * 152; idx += stride) {
        int d = idx / 152, e = idx - d * 152;
        Wt0[idx] = (d < 300 && e < 150) ? eW0[e * 300 + d] : 0.f;
    }
    for (int idx = tid; idx < 76 * 152; idx += stride) {
        int d = idx / 152, e = idx - d * 152;
        Wt1[idx] = (d < 74 && e < 150) ? eW1[e * 74 + d] : 0.f;
    }
    for (int idx = tid; idx < 36 * 152; idx += stride) {
        int d = idx / 152, e = idx - d * 152;
        Wt2[idx] = (d < 35 && e < 150) ? eW2[e * 35 + d] : 0.f;
    }
}

// ---------------- K1: fully fused enc -> attn -> cls. grid 256, block 768 ----------------
__global__ __launch_bounds__(NT, 1) void k_fused(
    const float* __restrict__ x0, const float* __restrict__ x1, const float* __restrict__ x2,
    const float* __restrict__ eb0, const float* __restrict__ eb1, const float* __restrict__ eb2,
    const float* __restrict__ Wt0, const float* __restrict__ Wt1, const float* __restrict__ Wt2,
    const float* __restrict__ WcT,
    const float* __restrict__ affw, const float* __restrict__ Ww, const float* __restrict__ Wh,
    const float* __restrict__ W1T, const float* __restrict__ cb1,
    const float* __restrict__ cW2, const float* __restrict__ cb2,
    float* __restrict__ out, Poly pc) {
    __shared__ __align__(16) float xs[NB * 428];   // x stage; later cls partial scratch
    __shared__ __align__(16) float featf[NB * 468]; // enc outputs; rows reused as hs
    __shared__ __align__(16) float fof[NB * 468];   // attn outputs (cls input)
    __shared__ __align__(16) float wWs[96], wHs[96];

    int tid = threadIdx.x;
    int b0 = blockIdx.x * NB;

    // ---- P0: stage x, small weights, zero feat pads ----
    if (tid < 96) { wWs[tid] = Ww[tid]; wHs[tid] = Wh[tid]; }
    if (tid >= 96 && tid < 192) {           // zero featf pads 456..467
        int q = tid - 96; int b = q / 12, r = q - b * 12;
        featf[b * 468 + 456 + r] = 0.f;
    }
    if (tid >= 192 && tid < 240) {          // zero fof segment pads (e=150,151)
        int q = tid - 192; int b = q / 6, r = q - b * 6;
        fof[b * 468 + (r >> 1) * 152 + 150 + (r & 1)] = 0.f;
    }
    for (int idx = tid; idx < NB * 75; idx += NT) {
        int b = idx / 75, q = idx - b * 75;
        ((float4*)(xs + b * 428))[q] = ((const float4*)(x0 + (size_t)(b0 + b) * 300))[q];
    }
    for (int idx = tid; idx < NB * 74; idx += NT) {
        int b = idx / 74, d = idx - b * 74;
        xs[b * 428 + 304 + d] = x1[(size_t)(b0 + b) * 74 + d];
    }
    for (int idx = tid; idx < NB * 35; idx += NT) {
        int b = idx / 35, d = idx - b * 35;
        xs[b * 428 + 380 + d] = x2[(size_t)(b0 + b) * 35 + d];
    }
    __syncthreads();

    // ---- P1: encoders. task = (m4 = t>>3, b = t&7): 8-lane W broadcast; 912 tasks ----
    {
        int tasks[2]; int nt = 1;
        tasks[0] = tid;
        if (tid >= 624) { tasks[nt++] = 768 + (767 - tid); }
        for (int q = 0; q < nt; ++q) {
            int task = tasks[q];
            int b = task & 7, m4 = task >> 3;
            int seg = (m4 >= 76) ? 2 : (m4 >= 38) ? 1 : 0;
            int e4 = m4 - seg * 38;
            const float* eb = seg == 0 ? eb0 : seg == 1 ? eb1 : eb2;
            const float4* Wt4 = (const float4*)(seg == 0 ? Wt0 : seg == 1 ? Wt1 : Wt2) + e4;
            const float* xb = xs + b * 428 + (seg == 0 ? 0 : seg == 1 ? 304 : 380);
            int DP4 = seg == 0 ? 76 : seg == 1 ? 19 : 9;
            const float4* xr = (const float4*)xb;
            int e = e4 * 4;
            float4 acc;
            acc.x = (e     < 150) ? eb[e]     : 0.f;
            acc.y = (e + 1 < 150) ? eb[e + 1] : 0.f;
            acc.z = (e + 2 < 150) ? eb[e + 2] : 0.f;
            acc.w = (e + 3 < 150) ? eb[e + 3] : 0.f;
            for (int d4 = 0; d4 < DP4; ++d4) {
                float4 x4 = xr[d4];
                float4 w0 = Wt4[(d4 * 4 + 0) * 38];
                float4 w1 = Wt4[(d4 * 4 + 1) * 38];
                float4 w2 = Wt4[(d4 * 4 + 2) * 38];
                float4 w3 = Wt4[(d4 * 4 + 3) * 38];
                FMA4(acc, x4.x, w0);
                FMA4(acc, x4.y, w1);
                FMA4(acc, x4.z, w2);
                FMA4(acc, x4.w, w3);
            }
            ((float4*)(featf + b * 468))[m4] = acc;
        }
    }
    __syncthreads();

    // ---- P2: attention. wave = (i = w>>2, wp = w&3); M-phase lane = hq(3b)|slice(3b),
    //      each lane covers BOTH b's of the pair (halves W traffic) ----
    {
        int w = tid >> 6;
        int i = w >> 2, wp = w & 3;
        int lane = tid & 63;
        int hq = lane & 7, slice = lane >> 3;          // 0..7 for M phase
        int slice2 = (lane >> 3) & 3, bh = lane >> 5;  // epilogue decode
        float aff = affw[i];
        const float4* Wb4 = (const float4*)WcT + (size_t)i * 3712 + hq;
        int bA = wp * 2, bB = bA + 1;
        const float4* frowA = (const float4*)(featf + bA * 468);
        const float4* frowB = (const float4*)(featf + bB * 468);

        float4 accA[NJ], accB[NJ];
        #pragma unroll
        for (int J = 0; J < NJ; ++J) {
            accA[J] = make_float4(0.f, 0.f, 0.f, 0.f);
            accB[J] = make_float4(0.f, 0.f, 0.f, 0.f);
        }
        float mxA = 0.f, mxB = 0.f;

        int m4lo = (slice < 4) ? slice * 15 : 60 + (slice - 4) * 14;
        int m4n  = (slice < 4) ? 15 : 14;
        #pragma unroll 3
        for (int k = 0; k < m4n; ++k) {
            int m4 = m4lo + k;
            float4 fA = frowA[m4];
            float4 fB = frowB[m4];
            const float4* wp4 = Wb4 + m4 * 32;
            float4 w0 = wp4[0];
            float4 w1 = wp4[8];
            float4 w2 = wp4[16];
            float4 w3 = wp4[24];
            mxA = fmaxf(mxA, fmaxf(fmaxf(fabsf(fA.x), fabsf(fA.y)), fmaxf(fabsf(fA.z), fabsf(fA.w))));
            mxB = fmaxf(mxB, fmaxf(fmaxf(fabsf(fB.x), fabsf(fB.y)), fmaxf(fabsf(fB.z), fabsf(fB.w))));
            {
                float g0 = aff * fA.x, g1 = aff * fA.y, g2 = aff * fA.z, g3 = aff * fA.w;
                float q0 = g0 * g0, q1 = g1 * g1, q2 = g2 * g2, q3 = g3 * g3;
                float p0 = g0, p1 = g1, p2 = g2, p3 = g3;
                FMA4(accA[0], p0, w0); FMA4(accA[0], p1, w1); FMA4(accA[0], p2, w2); FMA4(accA[0], p3, w3);
                #pragma unroll
                for (int J = 1; J < NJ; ++J) {
                    p0 *= q0; p1 *= q1; p2 *= q2; p3 *= q3;
                    FMA4(accA[J], p0, w0); FMA4(accA[J], p1, w1); FMA4(accA[J], p2, w2); FMA4(accA[J], p3, w3);
                }
            }
            {
                float g0 = aff * fB.x, g1 = aff * fB.y, g2 = aff * fB.z, g3 = aff * fB.w;
                float q0 = g0 * g0, q1 = g1 * g1, q2 = g2 * g2, q3 = g3 * g3;
                float p0 = g0, p1 = g1, p2 = g2, p3 = g3;
                FMA4(accB[0], p0, w0); FMA4(accB[0], p1, w1); FMA4(accB[0], p2, w2); FMA4(accB[0], p3, w3);
                #pragma unroll
                for (int J = 1; J < NJ; ++J) {
                    p0 *= q0; p1 *= q1; p2 *= q2; p3 *= q3;
                    FMA4(accB[J], p0, w0); FMA4(accB[J], p1, w1); FMA4(accB[J], p2, w2); FMA4(accB[J], p3, w3);
                }
            }
        }
        // reduce partial M across slice bits (8,16,32), fold poly coeff
        #pragma unroll
        for (int J = 0; J < NJ; ++J) {
            float cJ = pc.c[J];
            float vx, vy, vz, vw;
            vx = accA[J].x; vx += __shfl_xor(vx, 8); vx += __shfl_xor(vx, 16); vx += __shfl_xor(vx, 32);
            vy = accA[J].y; vy += __shfl_xor(vy, 8); vy += __shfl_xor(vy, 16); vy += __shfl_xor(vy, 32);
            vz = accA[J].z; vz += __shfl_xor(vz, 8); vz += __shfl_xor(vz, 16); vz += __shfl_xor(vz, 32);
            vw = accA[J].w; vw += __shfl_xor(vw, 8); vw += __shfl_xor(vw, 16); vw += __shfl_xor(vw, 32);
            accA[J].x = vx * cJ; accA[J].y = vy * cJ; accA[J].z = vz * cJ; accA[J].w = vw * cJ;
            vx = accB[J].x; vx += __shfl_xor(vx, 8); vx += __shfl_xor(vx, 16); vx += __shfl_xor(vx, 32);
            vy = accB[J].y; vy += __shfl_xor(vy, 8); vy += __shfl_xor(vy, 16); vy += __shfl_xor(vy, 32);
            vz = accB[J].z; vz += __shfl_xor(vz, 8); vz += __shfl_xor(vz, 16); vz += __shfl_xor(vz, 32);
            vw = accB[J].w; vw += __shfl_xor(vw, 8); vw += __shfl_xor(vw, 16); vw += __shfl_xor(vw, 32);
            accB[J].x = vx * cJ; accB[J].y = vy * cJ; accB[J].z = vz * cJ; accB[J].w = vw * cJ;
        }
        // full-row max for fallback guard
        mxA = fmaxf(mxA, __shfl_xor(mxA, 8));
        mxA = fmaxf(mxA, __shfl_xor(mxA, 16));
        mxA = fmaxf(mxA, __shfl_xor(mxA, 32));
        mxB = fmaxf(mxB, __shfl_xor(mxB, 8));
        mxB = fmaxf(mxB, __shfl_xor(mxB, 16));
        mxB = fmaxf(mxB, __shfl_xor(mxB, 32));

        // select this lane's epilogue row (compile-time J indexing; bh runtime -> cndmask)
        float4 Ms[NJ];
        #pragma unroll
        for (int J = 0; J < NJ; ++J) Ms[J] = bh ? accB[J] : accA[J];
        float gmax = fabsf(aff) * (bh ? mxB : mxA);
        int b = bA + bh;
        const float* fb = featf + b * 468;
        const float4* frow = bh ? frowB : frowA;

        // epilogue
        float4 wW4 = ((const float4*)wWs)[i * 8 + hq];
        float4 wH4 = ((const float4*)wHs)[i * 8 + hq];
        int e4lo = slice2 * 10;
        int e4hi = (slice2 == 3) ? 38 : (e4lo + 10);
        for (int e4 = e4lo; e4 < e4hi; ++e4) {
            float4 s4 = frow[i * 38 + e4];
            float ores[4];
            #pragma unroll
            for (int r = 0; r < 4; ++r) {
                float s = (r == 0) ? s4.x : (r == 1) ? s4.y : (r == 2) ? s4.z : s4.w;
                float4 a4;
                if (fabsf(s) * gmax <= X0f) {
                    float s2 = s * s, p = s;
                    a4.x = Ms[0].x * p; a4.y = Ms[0].y * p;
                    a4.z = Ms[0].z * p; a4.w = Ms[0].w * p;
                    #pragma unroll
                    for (int J = 1; J < NJ; ++J) { p *= s2; FMA4(a4, p, Ms[J]); }
                } else {
                    a4 = make_float4(0.f, 0.f, 0.f, 0.f);
                    for (int c = 0; c < 456; ++c) {
                        float t = tanhf(s * aff * fb[c]);
                        float4 wv = Wb4[c * 8];
                        FMA4(a4, t, wv);
                    }
                }
                float hx = fmaxf(fmaf(s, wW4.x, a4.x), 0.f);
                float hy = fmaxf(fmaf(s, wW4.y, a4.y), 0.f);
                float hz = fmaxf(fmaf(s, wW4.z, a4.z), 0.f);
                float hw = fmaxf(fmaf(s, wW4.w, a4.w), 0.f);
                float csum = hx * wH4.x + hy * wH4.y + hz * wH4.z + hw * wH4.w;
                csum += __shfl_xor(csum, 1);
                csum += __shfl_xor(csum, 2);
                csum += __shfl_xor(csum, 4);
                ores[r] = csum + s;
            }
            if (hq == 0)
                ((float4*)(fof + b * 468))[i * 38 + e4] = make_float4(ores[0], ores[1], ores[2], ores[3]);
        }
    }
    __syncthreads();

    // ---- P3: classifier stage 1. cs = tid>>8; b = tid&7 (8-lane W broadcast), k4 = (tid>>3)&31 ----
    {
        int cs = tid >> 8;
        int rr = tid & 255;
        int b = rr & 7, k4 = rr >> 3;
        const float4* W14 = (const float4*)W1T + k4;
        const float4* fr = (const float4*)(fof + b * 468);
        float4 a = make_float4(0.f, 0.f, 0.f, 0.f);
        int c4lo = cs * 38;
        for (int c4 = c4lo; c4 < c4lo + 38; ++c4) {
            float4 fv = fr[c4];
            float4 w0 = W14[(c4 * 4 + 0) * 32];
            float4 w1 = W14[(c4 * 4 + 1) * 32];
            float4 w2 = W14[(c4 * 4 + 2) * 32];
            float4 w3 = W14[(c4 * 4 + 3) * 32];
            FMA4(a, fv.x, w0);
            FMA4(a, fv.y, w1);
            FMA4(a, fv.z, w2);
            FMA4(a, fv.w, w3);
        }
        ((float4*)xs)[(cs * 8 + b) * 33 + k4] = a;  // xs reused as hpart
    }
    __syncthreads();
    if (tid < 256) {
        int b = tid >> 5, k4 = tid & 31;
        const float4* hp4 = (const float4*)xs;
        float4 v  = hp4[(0 * 8 + b) * 33 + k4];
        float4 v1 = hp4[(1 * 8 + b) * 33 + k4];
        float4 v2 = hp4[(2 * 8 + b) * 33 + k4];
        float4 bias = ((const float4*)cb1)[k4];
        v.x += v1.x + v2.x + bias.x;
        v.y += v1.y + v2.y + bias.y;
        v.z += v1.z + v2.z + bias.z;
        v.w += v1.w + v2.w + bias.w;
        ((float4*)(featf + b * 468))[k4] = v;  // feat row reused as hs[128]
    }
    __syncthreads();
    if (tid < NB * 7) {
        int b = tid / 7, o = tid - (tid / 7) * 7;
        const float* hb = featf + b * 468;
        const float* w2 = cW2 + o * 128;
        float acc = cb2[o];
        #pragma unroll 4
        for (int k = 0; k < 128; ++k) acc = fmaf(hb[k], w2[k], acc);
        out[(size_t)(b0 + b) * 7 + o] = acc;
    }
}

// ---------------- host: Chebyshev fit of tanh on [-1.1,1.1], odd monomials ----------------
static void make_poly(float* cf) {
    const double a = 1.1;
    const int NQ = 128;
    const double PI = 3.14159265358979323846;
    double b[DEG + 1];
    for (int k = 0; k <= DEG; ++k) b[k] = 0.0;
    for (int m = 0; m < NQ; ++m) {
        double th = PI * (m + 0.5) / NQ;
        double f = tanh(a * cos(th));
        for (int k = 1; k <= DEG; k += 2)
            b[k] += (2.0 / NQ) * f * cos(k * th);
    }
    double Tp[DEG + 1], Tc[DEG + 1], Tn[DEG + 1], mono[DEG + 1];
    for (int j = 0; j <= DEG; ++j) { Tp[j] = 0; Tc[j] = 0; mono[j] = 0; }
    Tp[0] = 1.0;
    Tc[1] = 1.0;
    for (int j = 0; j <= DEG; ++j) mono[j] += b[1] * Tc[j];
    for (int k = 2; k <= DEG; ++k) {
        for (int j = 0; j <= DEG; ++j) Tn[j] = -Tp[j];
        for (int j = 1; j <= DEG; ++j) Tn[j] += 2.0 * Tc[j - 1];
        for (int j = 0; j <= DEG; ++j) { Tp[j] = Tc[j]; Tc[j] = Tn[j]; }
        if (k & 1) for (int j = 0; j <= DEG; ++j) mono[j] += b[k] * Tc[j];
    }
    for (int J = 0; J < NJ; ++J) {
        int j = 2 * J + 1;
        cf[J] = (float)(mono[j] / pow(a, (double)j));
    }
}

extern "C" void kernel_launch(void* const* d_in, const int* in_sizes, int n_in,
                              void* d_out, int out_size, void* d_ws, size_t ws_size,
                              hipStream_t stream) {
    (void)in_sizes; (void)n_in; (void)out_size; (void)ws_size;
    const float* x0    = (const float*)d_in[0];
    const float* x1    = (const float*)d_in[1];
    const float* x2    = (const float*)d_in[2];
    const float* eW0   = (const float*)d_in[3];
    const float* eb0   = (const float*)d_in[4];
    const float* eW1   = (const float*)d_in[5];
    const float* eb1   = (const float*)d_in[6];
    const float* eW2   = (const float*)d_in[7];
    const float* eb2   = (const float*)d_in[8];
    const float* affw  = (const float*)d_in[9];
    const float* Ww    = (const float*)d_in[10];
    const float* Wc    = (const float*)d_in[11];
    const float* Wh    = (const float*)d_in[12];
    const float* cW1   = (const float*)d_in[13];
    const float* cb1   = (const float*)d_in[14];
    const float* cW2   = (const float*)d_in[15];
    const float* cb2   = (const float*)d_in[16];

    float* ws    = (float*)d_ws;
    float* wsWcT = ws;                 // 3*464*32  = 44544
    float* wsW1T = ws + 44544;         // 456*128   = 58368
    float* wsWt0 = ws + 102912;        // 304*152   = 46208
    float* wsWt1 = ws + 149120;        // 76*152    = 11552
    float* wsWt2 = ws + 160672;        // 36*152    = 5472

    Poly pc;
    make_poly(pc.c);

    k_repack<<<dim3(96), dim3(256), 0, stream>>>(Wc, cW1, eW0, eW1, eW2,
                                                 wsWcT, wsW1T, wsWt0, wsWt1, wsWt2);
    k_fused<<<dim3(256), dim3(NT), 0, stream>>>(x0, x1, x2, eb0, eb1, eb2,
                                                wsWt0, wsWt1, wsWt2, wsWcT,
                                                affw, Ww, Wh, wsW1T, cb1, cW2, cb2,
                                                (float*)d_out, pc);
}

// Round 12
// 66.037 us; speedup vs baseline: 1.0196x; 1.0196x over previous
//
#include <hip/hip_runtime.h>
#include <math.h>

#define NJ 4         // odd powers x^1..x^7
#define DEG 7
#define X0f 1.1f     // poly valid on [-1.1,1.1]; typical |s*g| ~ 0.4
#define NB 8         // batch rows per block
#define NT 768       // threads per block (12 waves)

struct Poly { float c[NJ]; };

typedef float v4f __attribute__((ext_vector_type(4)));

// ---------------- K0: repack weights ----------------
__global__ __launch_bounds__(256) void k_repack(
    const float* __restrict__ Wc, const float* __restrict__ W1,
    const float* __restrict__ eW0, const float* __restrict__ eW1, const float* __restrict__ eW2,
    float* __restrict__ WcT, float* __restrict__ W1T,
    float* __restrict__ Wt0, float* __restrict__ Wt1, float* __restrict__ Wt2) {
    int tid = blockIdx.x * 256 + threadIdx.x;
    int stride = gridDim.x * 256;
    for (int idx = tid; idx < 3 * 464 * 32; idx += stride) {
        int i = idx / (464 * 32); int rem = idx - i * 464 * 32;
        int m = rem >> 5, h = rem & 31;
        float v = 0.f;
        if (m < 456) {
            int seg = m / 152, e = m - seg * 152;
            if (e < 150) v = Wc[((size_t)i * 32 + h) * 450 + seg * 150 + e];
        }
        WcT[idx] = v;
    }
    for (int idx = tid; idx < 456 * 128; idx += stride) {
        int m = idx >> 7, k = idx & 127;
        int seg = m / 152, e = m - seg * 152;
        W1T[idx] = (e < 150) ? W1[k * 450 + seg * 150 + e] : 0.f;
    }
    for (int idx = tid; idx < 304 * 152; idx += stride) {
        int d = idx / 152, e = idx - d * 152;
        Wt0[idx] = (d < 300 && e < 150) ? eW0[e * 300 + d] : 0.f;
    }
    for (int idx = tid; idx < 76 * 152; idx += stride) {
        int d = idx / 152, e = idx - d * 152;
        Wt1[idx] = (d < 74 && e < 150) ? eW1[e * 74 + d] : 0.f;
    }
    for (int idx = tid; idx < 36 * 152; idx += stride) {
        int d = idx / 152, e = idx - d * 152;
        Wt2[idx] = (d < 35 && e < 150) ? eW2[e * 35 + d] : 0.f;
    }
}

// ---------------- K1: fully fused enc -> attn -> cls. grid 256, block 768 ----------------
__global__ __launch_bounds__(NT, 1) void k_fused(
    const float* __restrict__ x0, const float* __restrict__ x1, const float* __restrict__ x2,
    const float* __restrict__ eb0, const float* __restrict__ eb1, const float* __restrict__ eb2,
    const float* __restrict__ Wt0, const float* __restrict__ Wt1, const float* __restrict__ Wt2,
    const float* __restrict__ WcT,
    const float* __restrict__ affw, const float* __restrict__ Ww, const float* __restrict__ Wh,
    const float* __restrict__ W1T, const float* __restrict__ cb1,
    const float* __restrict__ cW2, const float* __restrict__ cb2,
    float* __restrict__ out, Poly pc) {
#pragma clang fp contract(fast)
    __shared__ __align__(16) float xs[NB * 428];   // x stage; later cls partial scratch
    __shared__ __align__(16) float featf[NB * 468]; // enc outputs; rows reused as hs
    __shared__ __align__(16) float fof[NB * 468];   // attn outputs (cls input)
    __shared__ __align__(16) float wWs[96], wHs[96];

    int tid = threadIdx.x;
    int b0 = blockIdx.x * NB;

    // ---- P0: stage x, small weights, zero feat pads ----
    if (tid < 96) { wWs[tid] = Ww[tid]; wHs[tid] = Wh[tid]; }
    if (tid >= 96 && tid < 192) {           // zero featf pads 456..467
        int q = tid - 96; int b = q / 12, r = q - b * 12;
        featf[b * 468 + 456 + r] = 0.f;
    }
    if (tid >= 192 && tid < 240) {          // zero fof segment pads (e=150,151)
        int q = tid - 192; int b = q / 6, r = q - b * 6;
        fof[b * 468 + (r >> 1) * 152 + 150 + (r & 1)] = 0.f;
    }
    for (int idx = tid; idx < NB * 75; idx += NT) {
        int b = idx / 75, q = idx - b * 75;
        ((v4f*)(xs + b * 428))[q] = ((const v4f*)(x0 + (size_t)(b0 + b) * 300))[q];
    }
    for (int idx = tid; idx < NB * 74; idx += NT) {
        int b = idx / 74, d = idx - b * 74;
        xs[b * 428 + 304 + d] = x1[(size_t)(b0 + b) * 74 + d];
    }
    for (int idx = tid; idx < NB * 35; idx += NT) {
        int b = idx / 35, d = idx - b * 35;
        xs[b * 428 + 380 + d] = x2[(size_t)(b0 + b) * 35 + d];
    }
    __syncthreads();

    // ---- P1: encoders. task = (m4 = t>>3, b = t&7): 8-lane W broadcast; 912 tasks ----
    {
        int tasks[2]; int nt = 1;
        tasks[0] = tid;
        if (tid >= 624) { tasks[nt++] = 768 + (767 - tid); }
        for (int q = 0; q < nt; ++q) {
            int task = tasks[q];
            int b = task & 7, m4 = task >> 3;
            int seg = (m4 >= 76) ? 2 : (m4 >= 38) ? 1 : 0;
            int e4 = m4 - seg * 38;
            const float* eb = seg == 0 ? eb0 : seg == 1 ? eb1 : eb2;
            const v4f* Wt4 = (const v4f*)(seg == 0 ? Wt0 : seg == 1 ? Wt1 : Wt2) + e4;
            const float* xb = xs + b * 428 + (seg == 0 ? 0 : seg == 1 ? 304 : 380);
            int DP4 = seg == 0 ? 76 : seg == 1 ? 19 : 9;
            const v4f* xr = (const v4f*)xb;
            int e = e4 * 4;
            v4f acc = { (e < 150) ? eb[e] : 0.f,
                        (e + 1 < 150) ? eb[e + 1] : 0.f,
                        (e + 2 < 150) ? eb[e + 2] : 0.f,
                        (e + 3 < 150) ? eb[e + 3] : 0.f };
            for (int d4 = 0; d4 < DP4; ++d4) {
                v4f x4 = xr[d4];
                v4f w0 = Wt4[(d4 * 4 + 0) * 38];
                v4f w1 = Wt4[(d4 * 4 + 1) * 38];
                v4f w2 = Wt4[(d4 * 4 + 2) * 38];
                v4f w3 = Wt4[(d4 * 4 + 3) * 38];
                acc += x4.x * w0;
                acc += x4.y * w1;
                acc += x4.z * w2;
                acc += x4.w * w3;
            }
            ((v4f*)(featf + b * 468))[m4] = acc;
        }
    }
    __syncthreads();

    // ---- P2: attention. wave = (i = w>>2, wp = w&3); M-phase lane = hq(3b)|slice(3b),
    //      each lane covers BOTH b's of the pair ----
    {
        int w = tid >> 6;
        int i = w >> 2, wp = w & 3;
        int lane = tid & 63;
        int hq = lane & 7, slice = lane >> 3;          // 0..7 for M phase
        int slice2 = (lane >> 3) & 3, bh = lane >> 5;  // epilogue decode
        float aff = affw[i];
        const v4f* Wb4 = (const v4f*)WcT + (size_t)i * 3712 + hq;
        int bA = wp * 2, bB = bA + 1;
        const v4f* frowA = (const v4f*)(featf + bA * 468);
        const v4f* frowB = (const v4f*)(featf + bB * 468);

        v4f accA[NJ], accB[NJ];
        #pragma unroll
        for (int J = 0; J < NJ; ++J) { accA[J] = (v4f)0.f; accB[J] = (v4f)0.f; }
        float mxA = 0.f, mxB = 0.f;

        int m4lo = (slice < 4) ? slice * 15 : 60 + (slice - 4) * 14;
        int m4n  = (slice < 4) ? 15 : 14;
        #pragma unroll 3
        for (int k = 0; k < m4n; ++k) {
            int m4 = m4lo + k;
            v4f fA = frowA[m4];
            v4f fB = frowB[m4];
            const v4f* wp4 = Wb4 + m4 * 32;
            v4f w0 = wp4[0];
            v4f w1 = wp4[8];
            v4f w2 = wp4[16];
            v4f w3 = wp4[24];
            mxA = fmaxf(mxA, fmaxf(fmaxf(fabsf(fA.x), fabsf(fA.y)), fmaxf(fabsf(fA.z), fabsf(fA.w))));
            mxB = fmaxf(mxB, fmaxf(fmaxf(fabsf(fB.x), fabsf(fB.y)), fmaxf(fabsf(fB.z), fabsf(fB.w))));
            {
                float g0 = aff * fA.x, g1 = aff * fA.y, g2 = aff * fA.z, g3 = aff * fA.w;
                float q0 = g0 * g0, q1 = g1 * g1, q2 = g2 * g2, q3 = g3 * g3;
                float p0 = g0, p1 = g1, p2 = g2, p3 = g3;
                accA[0] += p0 * w0; accA[0] += p1 * w1; accA[0] += p2 * w2; accA[0] += p3 * w3;
                #pragma unroll
                for (int J = 1; J < NJ; ++J) {
                    p0 *= q0; p1 *= q1; p2 *= q2; p3 *= q3;
                    accA[J] += p0 * w0; accA[J] += p1 * w1; accA[J] += p2 * w2; accA[J] += p3 * w3;
                }
            }
            {
                float g0 = aff * fB.x, g1 = aff * fB.y, g2 = aff * fB.z, g3 = aff * fB.w;
                float q0 = g0 * g0, q1 = g1 * g1, q2 = g2 * g2, q3 = g3 * g3;
                float p0 = g0, p1 = g1, p2 = g2, p3 = g3;
                accB[0] += p0 * w0; accB[0] += p1 * w1; accB[0] += p2 * w2; accB[0] += p3 * w3;
                #pragma unroll
                for (int J = 1; J < NJ; ++J) {
                    p0 *= q0; p1 *= q1; p2 *= q2; p3 *= q3;
                    accB[J] += p0 * w0; accB[J] += p1 * w1; accB[J] += p2 * w2; accB[J] += p3 * w3;
                }
            }
        }
        // reduce partial M across slice bits (8,16,32), fold poly coeff
        #pragma unroll
        for (int J = 0; J < NJ; ++J) {
            float cJ = pc.c[J];
            float vx, vy, vz, vw;
            vx = accA[J].x; vx += __shfl_xor(vx, 8); vx += __shfl_xor(vx, 16); vx += __shfl_xor(vx, 32);
            vy = accA[J].y; vy += __shfl_xor(vy, 8); vy += __shfl_xor(vy, 16); vy += __shfl_xor(vy, 32);
            vz = accA[J].z; vz += __shfl_xor(vz, 8); vz += __shfl_xor(vz, 16); vz += __shfl_xor(vz, 32);
            vw = accA[J].w; vw += __shfl_xor(vw, 8); vw += __shfl_xor(vw, 16); vw += __shfl_xor(vw, 32);
            accA[J] = (v4f){ vx * cJ, vy * cJ, vz * cJ, vw * cJ };
            vx = accB[J].x; vx += __shfl_xor(vx, 8); vx += __shfl_xor(vx, 16); vx += __shfl_xor(vx, 32);
            vy = accB[J].y; vy += __shfl_xor(vy, 8); vy += __shfl_xor(vy, 16); vy += __shfl_xor(vy, 32);
            vz = accB[J].z; vz += __shfl_xor(vz, 8); vz += __shfl_xor(vz, 16); vz += __shfl_xor(vz, 32);
            vw = accB[J].w; vw += __shfl_xor(vw, 8); vw += __shfl_xor(vw, 16); vw += __shfl_xor(vw, 32);
            accB[J] = (v4f){ vx * cJ, vy * cJ, vz * cJ, vw * cJ };
        }
        // full-row max for fallback guard
        mxA = fmaxf(mxA, __shfl_xor(mxA, 8));
        mxA = fmaxf(mxA, __shfl_xor(mxA, 16));
        mxA = fmaxf(mxA, __shfl_xor(mxA, 32));
        mxB = fmaxf(mxB, __shfl_xor(mxB, 8));
        mxB = fmaxf(mxB, __shfl_xor(mxB, 16));
        mxB = fmaxf(mxB, __shfl_xor(mxB, 32));

        // select this lane's epilogue row
        v4f Ms[NJ];
        #pragma unroll
        for (int J = 0; J < NJ; ++J) Ms[J] = bh ? accB[J] : accA[J];
        float gmax = fabsf(aff) * (bh ? mxB : mxA);
        int b = bA + bh;
        const float* fb = featf + b * 468;
        const v4f* frow = bh ? frowB : frowA;

        // epilogue
        v4f wW4 = ((const v4f*)wWs)[i * 8 + hq];
        v4f wH4 = ((const v4f*)wHs)[i * 8 + hq];
        int e4lo = slice2 * 10;
        int e4hi = (slice2 == 3) ? 38 : (e4lo + 10);
        for (int e4 = e4lo; e4 < e4hi; ++e4) {
            v4f s4 = frow[i * 38 + e4];
            float ores[4];
            #pragma unroll
            for (int r = 0; r < 4; ++r) {
                float s = (r == 0) ? s4.x : (r == 1) ? s4.y : (r == 2) ? s4.z : s4.w;
                v4f a4;
                if (fabsf(s) * gmax <= X0f) {
                    float s2 = s * s, p = s;
                    a4 = Ms[0] * p;
                    #pragma unroll
                    for (int J = 1; J < NJ; ++J) { p *= s2; a4 += p * Ms[J]; }
                } else {
                    a4 = (v4f)0.f;
                    for (int c = 0; c < 456; ++c) {
                        float t = tanhf(s * aff * fb[c]);
                        a4 += t * Wb4[c * 8];
                    }
                }
                v4f hv = s * wW4 + a4;
                hv = __builtin_elementwise_max(hv, (v4f)0.f);
                v4f dv = hv * wH4;
                float csum = dv.x + dv.y + dv.z + dv.w;
                csum += __shfl_xor(csum, 1);
                csum += __shfl_xor(csum, 2);
                csum += __shfl_xor(csum, 4);
                ores[r] = csum + s;
            }
            if (hq == 0)
                ((v4f*)(fof + b * 468))[i * 38 + e4] = (v4f){ ores[0], ores[1], ores[2], ores[3] };
        }
    }
    __syncthreads();

    // ---- P3: classifier stage 1. cs = tid>>8; b = tid&7 (8-lane W broadcast), k4 = (tid>>3)&31 ----
    {
        int cs = tid >> 8;
        int rr = tid & 255;
        int b = rr & 7, k4 = rr >> 3;
        const v4f* W14 = (const v4f*)W1T + k4;
        const v4f* fr = (const v4f*)(fof + b * 468);
        v4f a = (v4f)0.f;
        int c4lo = cs * 38;
        for (int c4 = c4lo; c4 < c4lo + 38; ++c4) {
            v4f fv = fr[c4];
            v4f w0 = W14[(c4 * 4 + 0) * 32];
            v4f w1 = W14[(c4 * 4 + 1) * 32];
            v4f w2 = W14[(c4 * 4 + 2) * 32];
            v4f w3 = W14[(c4 * 4 + 3) * 32];
            a += fv.x * w0;
            a += fv.y * w1;
            a += fv.z * w2;
            a += fv.w * w3;
        }
        ((v4f*)xs)[(cs * 8 + b) * 33 + k4] = a;  // xs reused as hpart
    }
    __syncthreads();
    if (tid < 256) {
        int b = tid >> 5, k4 = tid & 31;
        const v4f* hp4 = (const v4f*)xs;
        v4f v  = hp4[(0 * 8 + b) * 33 + k4];
        v4f v1 = hp4[(1 * 8 + b) * 33 + k4];
        v4f v2 = hp4[(2 * 8 + b) * 33 + k4];
        v4f bias = ((const v4f*)cb1)[k4];
        v = v + v1 + v2 + bias;
        ((v4f*)(featf + b * 468))[k4] = v;  // feat row reused as hs[128]
    }
    __syncthreads();
    if (tid < NB * 7) {
        int b = tid / 7, o = tid - (tid / 7) * 7;
        const v4f* hb = (const v4f*)(featf + b * 468);
        const v4f* w2 = (const v4f*)(cW2 + o * 128);
        v4f a4 = (v4f)0.f;
        #pragma unroll 8
        for (int k4 = 0; k4 < 32; ++k4) a4 += hb[k4] * w2[k4];
        out[(size_t)(b0 + b) * 7 + o] = cb2[o] + a4.x + a4.y + a4.z + a4.w;
    }
}

// ---------------- host: Chebyshev fit of tanh on [-1.1,1.1], odd monomials ----------------
static void make_poly(float* cf) {
    const double a = 1.1;
    const int NQ = 128;
    const double PI = 3.14159265358979323846;
    double b[DEG + 1];
    for (int k = 0; k <= DEG; ++k) b[k] = 0.0;
    for (int m = 0; m < NQ; ++m) {
        double th = PI * (m + 0.5) / NQ;
        double f = tanh(a * cos(th));
        for (int k = 1; k <= DEG; k += 2)
            b[k] += (2.0 / NQ) * f * cos(k * th);
    }
    double Tp[DEG + 1], Tc[DEG + 1], Tn[DEG + 1], mono[DEG + 1];
    for (int j = 0; j <= DEG; ++j) { Tp[j] = 0; Tc[j] = 0; mono[j] = 0; }
    Tp[0] = 1.0;
    Tc[1] = 1.0;
    for (int j = 0; j <= DEG; ++j) mono[j] += b[1] * Tc[j];
    for (int k = 2; k <= DEG; ++k) {
        for (int j = 0; j <= DEG; ++j) Tn[j] = -Tp[j];
        for (int j = 1; j <= DEG; ++j) Tn[j] += 2.0 * Tc[j - 1];
        for (int j = 0; j <= DEG; ++j) { Tp[j] = Tc[j]; Tc[j] = Tn[j]; }
        if (k & 1) for (int j = 0; j <= DEG; ++j) mono[j] += b[k] * Tc[j];
    }
    for (int J = 0; J < NJ; ++J) {
        int j = 2 * J + 1;
        cf[J] = (float)(mono[j] / pow(a, (double)j));
    }
}

extern "C" void kernel_launch(void* const* d_in, const int* in_sizes, int n_in,
                              void* d_out, int out_size, void* d_ws, size_t ws_size,
                              hipStream_t stream) {
    (void)in_sizes; (void)n_in; (void)out_size; (void)ws_size;
    const float* x0    = (const float*)d_in[0];
    const float* x1    = (const float*)d_in[1];
    const float* x2    = (const float*)d_in[2];
    const float* eW0   = (const float*)d_in[3];
    const float* eb0   = (const float*)d_in[4];
    const float* eW1   = (const float*)d_in[5];
    const float* eb1   = (const float*)d_in[6];
    const float* eW2   = (const float*)d_in[7];
    const float* eb2   = (const float*)d_in[8];
    const float* affw  = (const float*)d_in[9];
    const float* Ww    = (const float*)d_in[10];
    const float* Wc    = (const float*)d_in[11];
    const float* Wh    = (const float*)d_in[12];
    const float* cW1   = (const float*)d_in[13];
    const float* cb1   = (const float*)d_in[14];
    const float* cW2   = (const float*)d_in[15];
    const float* cb2   = (const float*)d_in[16];

    float* ws    = (float*)d_ws;
    float* wsWcT = ws;                 // 3*464*32  = 44544
    float* wsW1T = ws + 44544;         // 456*128   = 58368
    float* wsWt0 = ws + 102912;        // 304*152   = 46208
    float* wsWt1 = ws + 149120;        // 76*152    = 11552
    float* wsWt2 = ws + 160672;        // 36*152    = 5472

    Poly pc;
    make_poly(pc.c);

    k_repack<<<dim3(96), dim3(256), 0, stream>>>(Wc, cW1, eW0, eW1, eW2,
                                                 wsWcT, wsW1T, wsWt0, wsWt1, wsWt2);
    k_fused<<<dim3(256), dim3(NT), 0, stream>>>(x0, x1, x2, eb0, eb1, eb2,
                                                wsWt0, wsWt1, wsWt2, wsWcT,
                                                affw, Ww, Wh, wsW1T, cb1, cW2, cb2,
                                                (float*)d_out, pc);
}